// Round 1
// 1291.232 us; speedup vs baseline: 1.1311x; 1.1311x over previous
//
#include <hip/hip_runtime.h>
#include <math.h>

// InstantNGP hash-grid encoder, Round 3.
// R2 result: pass1 (level-major gather) 1150us, HBM 15%, VALU 6.6%, occ 89%
//   -> bound by the divergent-gather path: ~2.76 cyc per lane-gather, i.e. L2
//      line throughput (each random 8B gather drags a 64B line).
// R3 levers:
//  (a) Levels 0..4 (res^3 table small): pre-densify table[hash(x,y,z)] into a
//      dense grid stored as x-PAIRS (float4 = {c(x),c(x+1)}): 4 aligned 16B
//      gathers per point instead of 8 divergent 8B gathers -> half the lines.
//      Bit-exact (hash collisions baked into the dense grid).
//  (b) pass2 LDS row stride 18f2 -> 17f2: write phase was 8-way bank aliased
//      (2x the b64 floor); odd stride puts both phases at the LDS BW floor.

#define NLV 16
#define TSZ (1 << 19)
#define TMASK (TSZ - 1)
#define BLK 256
#define MAXDENSE 5          // levels 0..4: res 16,22,30,42,58 -> paired grids <= 3.1 MB < L2
#define ROWF2 17            // pass2 LDS row stride in float2 (odd -> conflict floor)
#define ROWF 34             // round-1 fallback LDS row stride (floats)

struct P16 {
    int r[NLV];
    int doff[MAXDENSE + 1]; // dense grid offsets (float4 units); doff[ndense] = total
    int ndense;
};

// ---------------- hash-path level encoder (levels >= ndense) ----------------
__device__ __forceinline__ float2 enc_level(
    const float px, const float py, const float pz,
    const int res, const float2* __restrict__ tl)
{
    const unsigned P1 = 2654435761u, P2 = 805459861u, P3 = 3674653429u;
    const float scale = (float)(res - 1);
    const float sx = px * scale, sy = py * scale, sz = pz * scale;
    const float fx = floorf(sx), fy = floorf(sy), fz = floorf(sz);
    const float wx = sx - fx, wy = sy - fy, wz = sz - fz;
    const int gx = (int)fx, gy = (int)fy, gz = (int)fz;
    const int rm = res - 1;
    const int x0 = min(max(gx, 0), rm), x1 = min(max(gx + 1, 0), rm);
    const int y0 = min(max(gy, 0), rm), y1 = min(max(gy + 1, 0), rm);
    const int z0 = min(max(gz, 0), rm), z1 = min(max(gz + 1, 0), rm);
    const unsigned hx0 = (unsigned)x0 * P1, hx1 = (unsigned)x1 * P1;
    const unsigned hy0 = (unsigned)y0 * P2, hy1 = (unsigned)y1 * P2;
    const unsigned hz0 = (unsigned)z0 * P3, hz1 = (unsigned)z1 * P3;

    const float2 c000 = tl[(hx0 ^ hy0 ^ hz0) & TMASK];
    const float2 c001 = tl[(hx0 ^ hy0 ^ hz1) & TMASK];
    const float2 c010 = tl[(hx0 ^ hy1 ^ hz0) & TMASK];
    const float2 c011 = tl[(hx0 ^ hy1 ^ hz1) & TMASK];
    const float2 c100 = tl[(hx1 ^ hy0 ^ hz0) & TMASK];
    const float2 c101 = tl[(hx1 ^ hy0 ^ hz1) & TMASK];
    const float2 c110 = tl[(hx1 ^ hy1 ^ hz0) & TMASK];
    const float2 c111 = tl[(hx1 ^ hy1 ^ hz1) & TMASK];

    const float ux = 1.f - wx, uy = 1.f - wy, uz = 1.f - wz;
    const float a00 = ux * uy, a01 = ux * wy, a10 = wx * uy, a11 = wx * wy;
    const float w000 = a00 * uz, w001 = a00 * wz;
    const float w010 = a01 * uz, w011 = a01 * wz;
    const float w100 = a10 * uz, w101 = a10 * wz;
    const float w110 = a11 * uz, w111 = a11 * wz;

    float acc0 = c000.x * w000;           float acc1 = c000.y * w000;
    acc0 += c001.x * w001;                acc1 += c001.y * w001;
    acc0 += c010.x * w010;                acc1 += c010.y * w010;
    acc0 += c011.x * w011;                acc1 += c011.y * w011;
    acc0 += c100.x * w100;                acc1 += c100.y * w100;
    acc0 += c101.x * w101;                acc1 += c101.y * w101;
    acc0 += c110.x * w110;                acc1 += c110.y * w110;
    acc0 += c111.x * w111;                acc1 += c111.y * w111;
    return make_float2(acc0, acc1);
}

// ---------------- dense-path level encoder (levels < ndense) ----------------
// G[cell] = {c(x), c(x+1)} pre-paired. gx clamped to res-2 so x+1 always valid;
// when floor rounds to res-1 exactly, wx becomes 1.0 and the result is identical
// to the reference's clip (weight of the shifted corner is 0).
__device__ __forceinline__ float2 enc_dense(
    const float px, const float py, const float pz,
    const int res, const float4* __restrict__ G)
{
    const float scale = (float)(res - 1);
    const float sx = px * scale, sy = py * scale, sz = pz * scale;
    int gx = (int)floorf(sx), gy = (int)floorf(sy), gz = (int)floorf(sz);
    gx = min(max(gx, 0), res - 2);
    gy = min(max(gy, 0), res - 2);
    gz = min(max(gz, 0), res - 2);
    const float wx = sx - (float)gx, wy = sy - (float)gy, wz = sz - (float)gz;

    const int r00 = (gz * res + gy) * res + gx;
    const int r10 = r00 + res;                 // y+1
    const int r01 = r00 + res * res;           // z+1
    const int r11 = r01 + res;                 // y+1, z+1
    const float4 v00 = G[r00];
    const float4 v10 = G[r10];
    const float4 v01 = G[r01];
    const float4 v11 = G[r11];

    const float ux = 1.f - wx, uy = 1.f - wy, uz = 1.f - wz;
    const float b00 = uy * uz, b10 = wy * uz, b01 = uy * wz, b11 = wy * wz;
    float acc0 = (v00.x * ux + v00.z * wx) * b00;
    float acc1 = (v00.y * ux + v00.w * wx) * b00;
    acc0 += (v10.x * ux + v10.z * wx) * b10;
    acc1 += (v10.y * ux + v10.w * wx) * b10;
    acc0 += (v01.x * ux + v01.z * wx) * b01;
    acc1 += (v01.y * ux + v01.w * wx) * b01;
    acc0 += (v11.x * ux + v11.z * wx) * b11;
    acc1 += (v11.y * ux + v11.w * wx) * b11;
    return make_float2(acc0, acc1);
}

// ---------------- dense grid builder: ~311K cells, runs once per launch ------
__global__ __launch_bounds__(BLK) void build_dense_kernel(
    const float* __restrict__ tab, float4* __restrict__ dg,
    const P16 pp, const int total)
{
    const unsigned P1 = 2654435761u, P2 = 805459861u, P3 = 3674653429u;
    const int i = blockIdx.x * BLK + threadIdx.x;
    if (i >= total) return;
    int l = 0;
    #pragma unroll
    for (int k = 1; k < MAXDENSE; ++k)
        if (k < pp.ndense && i >= pp.doff[k]) l = k;
    const int res = pp.r[l], rm = res - 1;
    const int id = i - pp.doff[l];
    const int x = id % res;
    const int t2 = id / res;
    const int y = t2 % res;
    const int z = t2 / res;
    const float2* T = ((const float2*)tab) + (long long)l * TSZ;
    const unsigned hyz = ((unsigned)y * P2) ^ ((unsigned)z * P3);
    const float2 lo = T[(((unsigned)x * P1) ^ hyz) & TMASK];
    const int x1 = min(x + 1, rm);
    const float2 hi = T[(((unsigned)x1 * P1) ^ hyz) & TMASK];
    dg[i] = make_float4(lo.x, lo.y, hi.x, hi.y);
}

// ---------------- Pass 1: level-major gather, coalesced ws write ----------------
__global__ __launch_bounds__(BLK) void pass1_kernel(
    const float* __restrict__ pos,
    const float* __restrict__ tab,
    float2* __restrict__ ws2,          // [NLV][npts] float2, level-major
    const float4* __restrict__ dense,  // paired dense grids, levels < ndense
    const P16 pp, const int npts, const int nblk_per_level)
{
    const int level = blockIdx.x / nblk_per_level;
    const int chunk = blockIdx.x % nblk_per_level;
    const long long n = (long long)chunk * BLK + threadIdx.x;
    if (n >= npts) return;

    const float px = pos[n * 3 + 0];
    const float py = pos[n * 3 + 1];
    const float pz = pos[n * 3 + 2];

    float2 f;
    if (level < pp.ndense) {
        f = enc_dense(px, py, pz, pp.r[level], dense + pp.doff[level]);
    } else {
        const float2* tl = ((const float2*)tab) + (long long)level * TSZ;
        f = enc_level(px, py, pz, pp.r[level], tl);
    }
    ws2[(long long)level * npts + n] = f;
}

// ---------------- Pass 2: transpose [L][N]f2 -> [N][L]f2 via LDS ----------------
// Row stride 17 f2 (odd): write phase banks (2t+2l)%32 -> 2-way (free);
// read phase banks (2pt+2fq)%32 -> 4-way = the b64 LDS bandwidth floor.
__global__ __launch_bounds__(BLK) void pass2_kernel(
    const float2* __restrict__ ws2,
    float2* __restrict__ out2,         // out viewed as [npts][16] float2
    const int npts)
{
    __shared__ float2 l2s[BLK * ROWF2];
    const int t = threadIdx.x;
    const long long p0 = (long long)blockIdx.x * BLK;
    const long long n = p0 + t;

    #pragma unroll
    for (int l = 0; l < NLV; ++l) {
        float2 v = make_float2(0.f, 0.f);
        if (n < npts) v = ws2[(long long)l * npts + n];
        l2s[t * ROWF2 + l] = v;
    }
    __syncthreads();

    const long long lim = (long long)npts * NLV;
    const long long obase = p0 * NLV;
    #pragma unroll
    for (int k = 0; k < NLV; ++k) {
        const int idx = k * BLK + t;
        const long long g = obase + idx;
        if (g < lim) {
            const int pt = idx >> 4;
            const int fq = idx & 15;
            out2[g] = l2s[pt * ROWF2 + fq];
        }
    }
}

// ---------------- Fallback (ws too small): round-1 fused kernel ----------------
__global__ __launch_bounds__(BLK) void fused_kernel(
    const float* __restrict__ pos,
    const float* __restrict__ tab,
    float* __restrict__ out,
    const P16 pp, const int npts)
{
    __shared__ float lds[BLK * ROWF];
    const int t = threadIdx.x;
    const long long blk = blockIdx.x;
    const long long n = blk * BLK + t;

    float px = 0.f, py = 0.f, pz = 0.f;
    if (n < npts) {
        px = pos[n * 3 + 0];
        py = pos[n * 3 + 1];
        pz = pos[n * 3 + 2];
    }
    for (int l = 0; l < NLV; ++l) {
        const float2* tl = ((const float2*)tab) + (long long)l * TSZ;
        const float2 f = enc_level(px, py, pz, pp.r[l], tl);
        lds[t * ROWF + 2 * l + 0] = f.x;
        lds[t * ROWF + 2 * l + 1] = f.y;
    }
    __syncthreads();
    float2* o2 = (float2*)out;
    const float2* l2 = (const float2*)lds;
    const long long obase = blk * (BLK * 16);
    const long long lim = (long long)npts * 16;
    #pragma unroll
    for (int k = 0; k < 16; ++k) {
        const long long g = obase + (long long)k * BLK + t;
        if (g < lim) {
            const int lp = (int)((g >> 4) - blk * BLK);
            const int fp = (int)(g & 15);
            o2[g] = l2[lp * 17 + fp];
        }
    }
}

extern "C" void kernel_launch(void* const* d_in, const int* in_sizes, int n_in,
                              void* d_out, int out_size, void* d_ws, size_t ws_size,
                              hipStream_t stream) {
    const float* pos = (const float*)d_in[0];
    const float* tab = (const float*)d_in[1];
    float* out = (float*)d_out;
    const int npts = in_sizes[0] / 3;
    if (npts <= 0) return;

    // Mirror reference float64 chain: _B = exp((log(2048)-log(16))/15);
    // res = min(int(16*_B**l), 2048)
    P16 pp;
    const double B = exp((log(2048.0) - log(16.0)) / 15.0);
    for (int l = 0; l < NLV; ++l) {
        const double v = 16.0 * pow(B, (double)l);
        int r = (int)v;
        if (r > 2048) r = 2048;
        pp.r[l] = r;
    }

    const size_t ws_needed = (size_t)NLV * npts * sizeof(float2);
    const int nblk = (npts + BLK - 1) / BLK;

    // Dense grids appended after ws2; clamp ndense to what fits.
    pp.ndense = 0;
    long long cum = 0;
    for (int l = 0; l < MAXDENSE; ++l) {
        const long long cells = (long long)pp.r[l] * pp.r[l] * pp.r[l];
        if (ws_needed + (size_t)(cum + cells) * sizeof(float4) <= ws_size) {
            pp.doff[l] = (int)cum;
            cum += cells;
            pp.ndense++;
        } else break;
    }
    for (int l = pp.ndense; l <= MAXDENSE; ++l) pp.doff[l] = (int)cum;

    if (ws_size >= ws_needed) {
        float2* ws2 = (float2*)d_ws;
        float4* dense = (float4*)((char*)d_ws + ws_needed);  // 16B-aligned (ws_needed % 16 == 0)
        if (pp.ndense > 0) {
            const int total = (int)cum;
            hipLaunchKernelGGL(build_dense_kernel, dim3((total + BLK - 1) / BLK), dim3(BLK),
                               0, stream, tab, dense, pp, total);
        }
        hipLaunchKernelGGL(pass1_kernel, dim3(nblk * NLV), dim3(BLK), 0, stream,
                           pos, tab, ws2, dense, pp, npts, nblk);
        hipLaunchKernelGGL(pass2_kernel, dim3(nblk), dim3(BLK), 0, stream,
                           ws2, (float2*)out, npts);
    } else {
        hipLaunchKernelGGL(fused_kernel, dim3(nblk), dim3(BLK), 0, stream,
                           pos, tab, out, pp, npts);
    }
}